// Round 7
// baseline (124.389 us; speedup 1.0000x reference)
//
#include <hip/hip_runtime.h>
#include <hip/hip_bf16.h>

typedef __attribute__((ext_vector_type(8))) short bf16x8;
typedef __attribute__((ext_vector_type(4))) float f32x4;

#define B_ROWS 4096
#define H_DIM  1024
#define TEMP_INV 20.0f
#define BM 256
#define BN 128
#define BK 32
#define NT (H_DIM / BK)    // 32 K-tiles
#define NBM (B_ROWS / BM)  // 16
#define NBN (B_ROWS / BN)  // 32

__device__ __forceinline__ void gload_lds16(const void* g, void* l) {
  __builtin_amdgcn_global_load_lds(
      (const __attribute__((address_space(1))) void*)g,
      (__attribute__((address_space(3))) void*)l, 16, 0, 0);
}

// Kernel 1: row-normalize (f32, cosine_similarity eps) and cast to bf16.
__global__ __launch_bounds__(256) void normalize_kernel(
    const float* __restrict__ cls, const float* __restrict__ hid,
    __hip_bfloat16* __restrict__ Abf, __hip_bfloat16* __restrict__ Bbf)
{
  const int w = threadIdx.x >> 6, lane = threadIdx.x & 63;
  const int r = blockIdx.x * 4 + w;                  // 0..8191
  const int rr = r & (B_ROWS - 1);
  const float* src = ((r < B_ROWS) ? cls : hid) + (size_t)rr * H_DIM;
  __hip_bfloat16* dst = ((r < B_ROWS) ? Abf : Bbf) + (size_t)rr * H_DIM;

  float4 v[4];
  float ss = 0.f;
  #pragma unroll
  for (int j = 0; j < 4; j++) {
    v[j] = reinterpret_cast<const float4*>(src)[j * 64 + lane];
    ss += v[j].x * v[j].x + v[j].y * v[j].y + v[j].z * v[j].z + v[j].w * v[j].w;
  }
  #pragma unroll
  for (int off = 1; off < 64; off <<= 1) ss += __shfl_xor(ss, off, 64);
  const float scale = 1.0f / fmaxf(sqrtf(ss), 1e-8f);

  #pragma unroll
  for (int j = 0; j < 4; j++) {
    union { ushort4 u; __hip_bfloat16 h[4]; } o;
    o.h[0] = __float2bfloat16(v[j].x * scale);
    o.h[1] = __float2bfloat16(v[j].y * scale);
    o.h[2] = __float2bfloat16(v[j].z * scale);
    o.h[3] = __float2bfloat16(v[j].w * scale);
    reinterpret_cast<ushort4*>(dst)[j * 64 + lane] = o.u;
  }
}

// Kernel 2: 256x128-tile NT-GEMM, 4 waves (2Mx2N, wave-tile 128x64), BK=32,
// TRIPLE-buffered 72 KiB LDS -> 2 blocks/CU (the co-resident block provides
// LDS<->MFMA overlap across barriers). One barrier per K-tile, counted
// vmcnt(6) = 2-K-tile prefetch cover. Swizzle: byte ^= (row&6)<<3
// (16B-preserving, exact 2-way bank aliasing = free), applied via
// inverse-swizzled gload source + swizzled ds_read.

#define STAGE_A(BUF, TT, C)                                                   \
  gload_lds16(Abase + (size_t)(row0 + (C) * 64 + srow) * 2048 + (TT) * 64 + scolb, \
              &As[BUF][(C) * 4096 + tid * 16])
#define STAGE_B(BUF, TT, C)                                                   \
  gload_lds16(Bbase + (size_t)(col0 + (C) * 64 + srow) * 2048 + (TT) * 64 + scolb, \
              &Bs[BUF][(C) * 4096 + tid * 16])

#define STAGE6(BUF, TT)                                                       \
  { STAGE_A(BUF, TT, 0); STAGE_A(BUF, TT, 1); STAGE_A(BUF, TT, 2);            \
    STAGE_A(BUF, TT, 3); STAGE_B(BUF, TT, 0); STAGE_B(BUF, TT, 1); }

#define RDFRAGS(BC)                                                           \
  { _Pragma("unroll") for (int mi = 0; mi < 8; mi++)                          \
      af[mi] = *(const bf16x8*)(&As[BC][rA + mi * 1024]);                     \
    _Pragma("unroll") for (int ni = 0; ni < 4; ni++)                          \
      bfr[ni] = *(const bf16x8*)(&Bs[BC][rB + ni * 1024]); }

#define MFMA32()                                                              \
  { __builtin_amdgcn_s_setprio(1);                                            \
    _Pragma("unroll") for (int mi = 0; mi < 8; mi++) {                        \
      _Pragma("unroll") for (int ni = 0; ni < 4; ni++) {                      \
        acc[mi][ni] = __builtin_amdgcn_mfma_f32_16x16x32_bf16(                \
            af[mi], bfr[ni], acc[mi][ni], 0, 0, 0); } }                       \
    __builtin_amdgcn_s_setprio(0); }

#define BARB() __builtin_amdgcn_s_barrier()

#define ITER_F(BC, BN_, T_)                                                   \
  { STAGE6(BN_, (T_) + 2); RDFRAGS(BC); MFMA32();                             \
    asm volatile("s_waitcnt vmcnt(6)" ::: "memory"); BARB(); }
#define ITER_W0(BC)                                                           \
  { RDFRAGS(BC); MFMA32();                                                    \
    asm volatile("s_waitcnt vmcnt(0)" ::: "memory"); BARB(); }
#define ITER_L(BC)                                                            \
  { RDFRAGS(BC); MFMA32(); }

__global__ __launch_bounds__(256, 2) void gemm_kernel(
    const __hip_bfloat16* __restrict__ A, const __hip_bfloat16* __restrict__ Bm,
    float* __restrict__ pp, float* __restrict__ diag)
{
  __shared__ __align__(16) char As[3][16384];   // [3 buf][256 rows][32 cols] bf16
  __shared__ __align__(16) char Bs[3][8192];    // [3 buf][128 rows][32 cols] bf16

  const int tid  = threadIdx.x;
  const int lane = tid & 63;
  const int w    = tid >> 6;            // 0..3
  const int wm   = w >> 1, wn = w & 1;  // 2 x 2 wave grid, wave-tile 128x64

  // XCD-aware bijective swizzle (512 blocks, 512%8==0):
  // XCD x gets bm in {2x,2x+1} (A-panel 1MB, L2-resident) x all bn.
  const int fid = blockIdx.y * NBN + blockIdx.x;
  const int swz = (fid & 7) * 64 + (fid >> 3);
  const int bm = swz >> 5, bn = swz & 31;

  const long row0 = (long)bm * BM, col0 = (long)bn * BN;
  const char* Abase = (const char*)A;
  const char* Bbase = (const char*)Bm;

  // Stage addressing: thread t writes LDS linearly at chunk*4096 + t*16.
  // Phys slot (t&3) of row (t>>2) holds logical slot (t&3)^((row>>1)&3).
  const int srow  = tid >> 2;                                   // 0..63 in chunk
  const int scolb = (((tid & 3) ^ ((tid >> 3) & 3)) << 4);      // swizzled col byte

  // Read addressing: row = <base>+fr, slot ks16=(lane>>4); phys byte =
  // row*64 + (ks16*16 ^ ((fr&6)<<3)).  (row&6 == fr&6 for all fragments.)
  const int fr  = lane & 15;
  const int xsl = ((lane >> 4) * 16) ^ ((fr & 6) << 3);
  const int rA  = (wm * 128 + fr) * 64 + xsl;
  const int rB  = (wn * 64  + fr) * 64 + xsl;

  f32x4 acc[8][4] = {};
  bf16x8 af[8], bfr[4];

  // Prologue: stage T0->buf0, T1->buf1; wait T0's 6; barrier.
  STAGE6(0, 0);
  STAGE6(1, 1);
  asm volatile("s_waitcnt vmcnt(6)" ::: "memory");
  BARB();

  #pragma unroll 1
  for (int T = 0; T < 30; T += 3) {
    ITER_F(0, 2, T);
    ITER_F(1, 0, T + 1);
    ITER_F(2, 1, T + 2);
  }
  ITER_W0(0);        // T=30
  ITER_L(1);         // T=31

  // ---- Epilogue (no atomics) ----
  const bool isdiag = ((bn >> 1) == bm);
  const int g = lane >> 4;            // C/D: row=(lane>>4)*4+r, col=lane&15
  __syncthreads();                    // safe LDS reuse point
  float* lds_p = (float*)&As[0][0];   // [2 wn][256 rows] = 2 KB

  #pragma unroll
  for (int m = 0; m < 8; m++) {
    const int rowb = (int)row0 + wm * 128 + m * 16 + g * 4;
    float p[4] = {0.f, 0.f, 0.f, 0.f};
    #pragma unroll
    for (int n = 0; n < 4; n++) {
      const int colb = (int)col0 + wn * 64 + n * 16 + fr;
      #pragma unroll
      for (int r = 0; r < 4; r++) {
        float sim = acc[m][n][r] * TEMP_INV;
        if (isdiag && (rowb + r == colb)) diag[rowb + r] = sim;
        p[r] += __expf(sim);
      }
    }
    #pragma unroll
    for (int r = 0; r < 4; r++) {
      float s = p[r];
      s += __shfl_xor(s, 1, 64);
      s += __shfl_xor(s, 2, 64);
      s += __shfl_xor(s, 4, 64);
      s += __shfl_xor(s, 8, 64);
      if (fr == 0)
        lds_p[wn * 256 + wm * 128 + m * 16 + g * 4 + r] = s;
    }
  }
  __syncthreads();
  {
    float s = lds_p[tid] + lds_p[256 + tid];
    pp[(size_t)bn * B_ROWS + row0 + tid] = s;   // coalesced, non-atomic
  }
}

// Kernel 3: out = mean(log(sum_bn pp[bn][i]) - diag[i])
__global__ __launch_bounds__(1024) void finalize_kernel(
    const float* __restrict__ pp, const float* __restrict__ diag,
    float* __restrict__ out)
{
  int tid = threadIdx.x;
  float acc = 0.f;
  for (int i = tid; i < B_ROWS; i += 1024) {
    float s = 0.f;
    #pragma unroll
    for (int j = 0; j < NBN; j++) s += pp[(size_t)j * B_ROWS + i];
    acc += logf(s) - diag[i];
  }
  #pragma unroll
  for (int off = 1; off < 64; off <<= 1) acc += __shfl_xor(acc, off, 64);
  __shared__ float wsum[16];
  if ((tid & 63) == 0) wsum[tid >> 6] = acc;
  __syncthreads();
  if (tid == 0) {
    float t = 0.f;
    #pragma unroll
    for (int i = 0; i < 16; i++) t += wsum[i];
    out[0] = t * (1.0f / B_ROWS);
  }
}

extern "C" void kernel_launch(void* const* d_in, const int* in_sizes, int n_in,
                              void* d_out, int out_size, void* d_ws, size_t ws_size,
                              hipStream_t stream)
{
  const float* cls = (const float*)d_in[0];
  const float* hid = (const float*)d_in[1];
  float* out = (float*)d_out;
  char* ws = (char*)d_ws;

  __hip_bfloat16* Abf = (__hip_bfloat16*)ws;                                // 8 MB
  __hip_bfloat16* Bbf = (__hip_bfloat16*)(ws + (size_t)B_ROWS * H_DIM * 2); // 8 MB
  float* pp   = (float*)(ws + (size_t)B_ROWS * H_DIM * 4);                  // 512 KB
  float* diag = pp + (size_t)NBN * B_ROWS;                                  // 16 KB

  hipLaunchKernelGGL(normalize_kernel, dim3(2 * B_ROWS / 4), dim3(256), 0, stream,
                     cls, hid, Abf, Bbf);
  hipLaunchKernelGGL(gemm_kernel, dim3(NBN, NBM), dim3(256), 0, stream,
                     Abf, Bbf, pp, diag);
  hipLaunchKernelGGL(finalize_kernel, dim3(1), dim3(1024), 0, stream,
                     pp, diag, out);
}

// Round 8
// 113.316 us; speedup vs baseline: 1.0977x; 1.0977x over previous
//
#include <hip/hip_runtime.h>
#include <hip/hip_bf16.h>

typedef __attribute__((ext_vector_type(8))) short bf16x8;
typedef __attribute__((ext_vector_type(4))) float f32x4;

#define B_ROWS 4096
#define H_DIM  1024
#define TEMP_INV 20.0f
#define BM 256
#define BK 32
#define NT (H_DIM / BK)    // 32 K-tiles
#define NBN (B_ROWS / BM)  // 16

__device__ __forceinline__ void gload_lds16(const void* g, void* l) {
  __builtin_amdgcn_global_load_lds(
      (const __attribute__((address_space(1))) void*)g,
      (__attribute__((address_space(3))) void*)l, 16, 0, 0);
}

// Kernel 1: row-normalize (f32, cosine_similarity eps) and cast to bf16.
// Block 0 also zeroes the output accumulator (finalize atomicAdds into it).
__global__ __launch_bounds__(256) void normalize_kernel(
    const float* __restrict__ cls, const float* __restrict__ hid,
    __hip_bfloat16* __restrict__ Abf, __hip_bfloat16* __restrict__ Bbf,
    float* __restrict__ out)
{
  if (blockIdx.x == 0 && threadIdx.x == 0) out[0] = 0.0f;
  const int w = threadIdx.x >> 6, lane = threadIdx.x & 63;
  const int r = blockIdx.x * 4 + w;                  // 0..8191
  const int rr = r & (B_ROWS - 1);
  const float* src = ((r < B_ROWS) ? cls : hid) + (size_t)rr * H_DIM;
  __hip_bfloat16* dst = ((r < B_ROWS) ? Abf : Bbf) + (size_t)rr * H_DIM;

  float4 v[4];
  float ss = 0.f;
  #pragma unroll
  for (int j = 0; j < 4; j++) {
    v[j] = reinterpret_cast<const float4*>(src)[j * 64 + lane];
    ss += v[j].x * v[j].x + v[j].y * v[j].y + v[j].z * v[j].z + v[j].w * v[j].w;
  }
  #pragma unroll
  for (int off = 1; off < 64; off <<= 1) ss += __shfl_xor(ss, off, 64);
  const float scale = 1.0f / fmaxf(sqrtf(ss), 1e-8f);

  #pragma unroll
  for (int j = 0; j < 4; j++) {
    union { ushort4 u; __hip_bfloat16 h[4]; } o;
    o.h[0] = __float2bfloat16(v[j].x * scale);
    o.h[1] = __float2bfloat16(v[j].y * scale);
    o.h[2] = __float2bfloat16(v[j].z * scale);
    o.h[3] = __float2bfloat16(v[j].w * scale);
    reinterpret_cast<ushort4*>(dst)[j * 64 + lane] = o.u;
  }
}

// Kernel 2: 256x256-tile NT-GEMM, 8 waves (2Mx4N, wave-tile 128x64), BK=32,
// QUAD-buffered 128 KiB LDS, prefetch 3 K-tiles ahead (12 gloads / 24 KB in
// flight per CU — covers HBM latency; prior rounds' 12 KB was the limiter).
// One barrier per K-tile; counted vmcnt(8) retires exactly tile T+1.
// Swizzle byte ^= (row&6)<<3 (2-way = free) via inverse-swizzled gload
// source + swizzled ds_read. Fused exp epilogue, no atomics in gemm.

#define STAGE4(BUF, TT)                                                       \
  { gload_lds16(Abase + (size_t)(row0 + 0   + srow) * 2048 + (TT) * 64 + scolb, \
                &As[BUF][tid * 16]);                                          \
    gload_lds16(Abase + (size_t)(row0 + 128 + srow) * 2048 + (TT) * 64 + scolb, \
                &As[BUF][8192 + tid * 16]);                                   \
    gload_lds16(Bbase + (size_t)(col0 + 0   + srow) * 2048 + (TT) * 64 + scolb, \
                &Bs[BUF][tid * 16]);                                          \
    gload_lds16(Bbase + (size_t)(col0 + 128 + srow) * 2048 + (TT) * 64 + scolb, \
                &Bs[BUF][8192 + tid * 16]); }

#define RDFRAGS(BC)                                                           \
  { _Pragma("unroll") for (int mi = 0; mi < 8; mi++)                          \
      af[mi] = *(const bf16x8*)(&As[BC][rA + mi * 1024]);                     \
    _Pragma("unroll") for (int ni = 0; ni < 4; ni++)                          \
      bfr[ni] = *(const bf16x8*)(&Bs[BC][rB + ni * 1024]); }

#define MFMA32()                                                              \
  { __builtin_amdgcn_s_setprio(1);                                            \
    _Pragma("unroll") for (int mi = 0; mi < 8; mi++) {                        \
      _Pragma("unroll") for (int ni = 0; ni < 4; ni++) {                      \
        acc[mi][ni] = __builtin_amdgcn_mfma_f32_16x16x32_bf16(                \
            af[mi], bfr[ni], acc[mi][ni], 0, 0, 0); } }                       \
    __builtin_amdgcn_s_setprio(0); }

#define BARB() __builtin_amdgcn_s_barrier()

// Steady-state iteration: stage T+3 into (BC+3)&3, read/compute BC, retire T+1.
#define ITER_F(T_, BC)                                                        \
  { STAGE4((BC + 3) & 3, (T_) + 3); RDFRAGS(BC); MFMA32();                    \
    asm volatile("s_waitcnt vmcnt(8)" ::: "memory"); BARB(); }

__global__ __launch_bounds__(512, 2) void gemm_kernel(
    const __hip_bfloat16* __restrict__ A, const __hip_bfloat16* __restrict__ Bm,
    float* __restrict__ pp, float* __restrict__ diag)
{
  __shared__ __align__(16) char As[4][16384];   // [4 buf][256 rows][32 cols] bf16
  __shared__ __align__(16) char Bs[4][16384];

  const int tid  = threadIdx.x;
  const int lane = tid & 63;
  const int w    = tid >> 6;            // 0..7
  const int wm   = w >> 2, wn = w & 3;  // 2 x 4 wave grid, wave-tile 128x64

  // XCD-aware bijective swizzle (256 blocks, 256%8==0).
  const int fid = blockIdx.y * NBN + blockIdx.x;
  const int swz = (fid & 7) * 32 + (fid >> 3);
  const int bm = swz >> 4, bn = swz & 15;

  const long row0 = (long)bm * BM, col0 = (long)bn * BM;
  const char* Abase = (const char*)A;
  const char* Bbase = (const char*)Bm;

  // Stage addressing: 512 threads, 4 thr/row x 16B = 64-B rows, 128 rows/call.
  // Phys slot (t&3) of row holds logical slot (t&3)^((row>>1)&3).
  const int srow  = tid >> 2;                                   // 0..127
  const int scolb = (((tid & 3) ^ ((tid >> 3) & 3)) << 4);      // swizzled col byte

  // Read addressing: row base + fr; phys slot = ks ^ ((fr>>1)&3).
  const int fr  = lane & 15;
  const int xsl = ((lane >> 4) * 16) ^ ((fr & 6) << 3);
  const int rA  = (wm * 128 + fr) * 64 + xsl;
  const int rB  = (wn * 64  + fr) * 64 + xsl;

  f32x4 acc[8][4] = {};
  bf16x8 af[8], bfr[4];

  // Prologue: stage T0,T1,T2 (12 loads); retire T0; barrier.
  STAGE4(0, 0);
  STAGE4(1, 1);
  STAGE4(2, 2);
  asm volatile("s_waitcnt vmcnt(8)" ::: "memory");
  BARB();

  #pragma unroll 1
  for (int T = 0; T < 28; T += 4) {
    ITER_F(T,     0);
    ITER_F(T + 1, 1);
    ITER_F(T + 2, 2);
    ITER_F(T + 3, 3);
  }
  // T=28: stage T+3=31 (last), retire 29.
  { STAGE4(3, 31); RDFRAGS(0); MFMA32();
    asm volatile("s_waitcnt vmcnt(8)" ::: "memory"); BARB(); }
  // T=29: retire 30.
  { RDFRAGS(1); MFMA32();
    asm volatile("s_waitcnt vmcnt(4)" ::: "memory"); BARB(); }
  // T=30: retire 31.
  { RDFRAGS(2); MFMA32();
    asm volatile("s_waitcnt vmcnt(0)" ::: "memory"); BARB(); }
  // T=31.
  { RDFRAGS(3); MFMA32(); }

  // ---- Epilogue (no atomics) ----
  const bool isdiag = (bm == bn);
  const int g = lane >> 4;            // C/D: row=(lane>>4)*4+r, col=lane&15
  __syncthreads();                    // safe LDS reuse point
  float* lds_p = (float*)&As[0][0];   // [4 wn][256 rows] = 4 KB

  #pragma unroll
  for (int m = 0; m < 8; m++) {
    const int rowb = (int)row0 + wm * 128 + m * 16 + g * 4;
    float p[4] = {0.f, 0.f, 0.f, 0.f};
    #pragma unroll
    for (int n = 0; n < 4; n++) {
      const int colb = (int)col0 + wn * 64 + n * 16 + fr;
      #pragma unroll
      for (int r = 0; r < 4; r++) {
        float sim = acc[m][n][r] * TEMP_INV;
        if (isdiag && (rowb + r == colb)) diag[rowb + r] = sim;
        p[r] += __expf(sim);
      }
    }
    #pragma unroll
    for (int r = 0; r < 4; r++) {
      float s = p[r];
      s += __shfl_xor(s, 1, 64);
      s += __shfl_xor(s, 2, 64);
      s += __shfl_xor(s, 4, 64);
      s += __shfl_xor(s, 8, 64);
      if (fr == 0)
        lds_p[wn * 256 + wm * 128 + m * 16 + g * 4 + r] = s;
    }
  }
  __syncthreads();
  if (tid < 256) {
    float s = lds_p[tid] + lds_p[256 + tid] + lds_p[512 + tid] + lds_p[768 + tid];
    pp[(size_t)bn * B_ROWS + row0 + tid] = s;   // coalesced, non-atomic
  }
}

// Kernel 3: out += sum(log(sum_bn pp) - diag)/B over this block's rows.
__global__ __launch_bounds__(256) void finalize_kernel(
    const float* __restrict__ pp, const float* __restrict__ diag,
    float* __restrict__ out)
{
  const int tid = threadIdx.x;
  const int i = blockIdx.x * 256 + tid;
  float s = 0.f;
  #pragma unroll
  for (int j = 0; j < NBN; j++) s += pp[(size_t)j * B_ROWS + i];
  float acc = logf(s) - diag[i];
  #pragma unroll
  for (int off = 1; off < 64; off <<= 1) acc += __shfl_xor(acc, off, 64);
  __shared__ float wsum[4];
  if ((tid & 63) == 0) wsum[tid >> 6] = acc;
  __syncthreads();
  if (tid == 0) {
    float t = wsum[0] + wsum[1] + wsum[2] + wsum[3];
    atomicAdd(out, t * (1.0f / B_ROWS));
  }
}

extern "C" void kernel_launch(void* const* d_in, const int* in_sizes, int n_in,
                              void* d_out, int out_size, void* d_ws, size_t ws_size,
                              hipStream_t stream)
{
  const float* cls = (const float*)d_in[0];
  const float* hid = (const float*)d_in[1];
  float* out = (float*)d_out;
  char* ws = (char*)d_ws;

  __hip_bfloat16* Abf = (__hip_bfloat16*)ws;                                // 8 MB
  __hip_bfloat16* Bbf = (__hip_bfloat16*)(ws + (size_t)B_ROWS * H_DIM * 2); // 8 MB
  float* pp   = (float*)(ws + (size_t)B_ROWS * H_DIM * 4);                  // 256 KB
  float* diag = pp + (size_t)NBN * B_ROWS;                                  // 16 KB

  hipLaunchKernelGGL(normalize_kernel, dim3(2 * B_ROWS / 4), dim3(256), 0, stream,
                     cls, hid, Abf, Bbf, out);
  hipLaunchKernelGGL(gemm_kernel, dim3(NBN, NBN), dim3(512), 0, stream,
                     Abf, Bbf, pp, diag);
  hipLaunchKernelGGL(finalize_kernel, dim3(B_ROWS / 256), dim3(256), 0, stream,
                     pp, diag, out);
}